// Round 5
// baseline (312.920 us; speedup 1.0000x reference)
//
#include <hip/hip_runtime.h>
#include <math.h>

#define NB 32
#define CB 256
#define HB 56
#define WB 56
#define PLANE 3136           // floats per (n,c) plane
#define PLANE4 784           // float4 per plane
#define CL 56
#define POOLSZ (NB*CB*CL)
#define NCHUNK 1024          // 8-plane chunks
#define TBLN 1792            // table floats per chunk: H0|W0g|H1|W1g (448 each)

__device__ inline float wave_sum(float v) {
    #pragma unroll
    for (int o = 32; o; o >>= 1) v += __shfl_xor(v, o, 64);
    return v;
}

// ---------------- Kernel 1: pooling. 4096 blocks, 2 planes (verified) -----------
__global__ __launch_bounds__(256) void k_pool(const float* __restrict__ x,
        float* __restrict__ ph, float* __restrict__ pw,
        float* __restrict__ mh, float* __restrict__ mw, float* __restrict__ gap) {
    __shared__ float tile[2 * 3192];          // two 56x57 planes, 25.5 KB
    const int t = threadIdx.x, wv = t >> 6, ln = t & 63;
    const int pA = blockIdx.x * 2;
    const float4* x4 = (const float4*)(x + (size_t)pA * PLANE);

    float4 v[6];
    #pragma unroll
    for (int u = 0; u < 6; ++u) v[u] = x4[t + u * 256];
    float4 vt;
    const bool tail = t < 32;
    if (tail) vt = x4[t + 1536];
    #pragma unroll
    for (int u = 0; u < 6; ++u) {
        int j = t + u * 256;
        int pl = j >= PLANE4, jj = j - pl * PLANE4;
        int h = jj / 14, wq = jj - h * 14;
        float* d = &tile[pl * 3192 + h * 57 + wq * 4];
        d[0] = v[u].x; d[1] = v[u].y; d[2] = v[u].z; d[3] = v[u].w;
    }
    if (tail) {
        int j = t + 1536;
        int jj = j - PLANE4;                  // always plane 1
        int h = jj / 14, wq = jj - h * 14;
        float* d = &tile[3192 + h * 57 + wq * 4];
        d[0] = vt.x; d[1] = vt.y; d[2] = vt.z; d[3] = vt.w;
    }
    __syncthreads();

    const int pl = wv >> 1;                   // waves 0,1 -> plane A; 2,3 -> B
    const float* tb = &tile[pl * 3192];
    const size_t pidx = (size_t)(pA + pl) * CL;
    if (!(wv & 1)) {                          // even wave: column scans
        if (ln < CL) {
            float s = 0.f, m = -INFINITY;
            #pragma unroll 8
            for (int h = 0; h < HB; ++h) { float vv = tb[h * 57 + ln]; s += vv; m = fmaxf(m, vv); }
            pw[pidx + ln] = s * (1.f / HB);
            mw[pidx + ln] = m;
        }
    } else {                                  // odd wave: row scans + gap
        float s = 0.f, m = -INFINITY;
        if (ln < CL) {
            #pragma unroll 8
            for (int wq = 0; wq < WB; ++wq) { float vv = tb[ln * 57 + wq]; s += vv; m = fmaxf(m, vv); }
            ph[pidx + ln] = s * (1.f / WB);
            mh[pidx + ln] = m;
        }
        float tot = wave_sum(s);              // lanes >=56 contribute 0
        if (ln == 0) gap[pA + pl] = tot * (1.f / PLANE);
    }
}

// ---------------- Kernel 2: y (redundant) + g (redundant) + tables + tsum -------
// 1024 blocks x 256 thr; block gq owns planes q0..q0+7 (n = gq>>5, c0 = (gq&31)*8)
__global__ __launch_bounds__(256) void k_bt(const float* __restrict__ x,
        const float* __restrict__ ph, const float* __restrict__ pw,
        const float* __restrict__ mh, const float* __restrict__ mw,
        const float* __restrict__ gap,
        const float* __restrict__ w1, const float* __restrict__ b1,
        const float* __restrict__ gamma, const float* __restrict__ beta,
        const float* __restrict__ rmean, const float* __restrict__ rvar,
        const float* __restrict__ gw1, const float* __restrict__ gw2,
        const float* __restrict__ gb2,
        const float* __restrict__ wh, const float* __restrict__ bh,
        const float* __restrict__ ww, const float* __restrict__ bw,
        float* __restrict__ tvec, float* __restrict__ tbl) {
    __shared__ float lw1[8 * CB];             // 2048
    __shared__ float tile[32 * 113];          // 3616: 32-channel pool slice
    __shared__ float yl[1792];                // y[br][m][l]
    __shared__ __align__(16) float tb[1792];  // H0|W0*g0|H1|W1*g1
    __shared__ float red[256];
    __shared__ float hid[64];
    __shared__ float part[32];
    __shared__ float gg[2];
    const int t = threadIdx.x, wv = t >> 6, ln = t & 63;
    const int gq = blockIdx.x;
    const int n = gq >> 5, c0 = (gq & 31) * 8;
    const int q0 = gq * 8;                    // == n*256 + c0

    for (int i = t; i < 8 * CB; i += 256) lw1[i] = w1[i];

    // gate hidden-layer partials (gap/gw1 L2-hot)
    {
        int j = t & 63, ch = t >> 6;
        const float* gv = gap + n * CB + ch * 64;
        const float* wp = gw1 + (size_t)j * CB + ch * 64;
        float a = 0.f;
        #pragma unroll 8
        for (int c = 0; c < 64; ++c) a += gv[c] * wp[c];
        red[j * 4 + ch] = a;
    }

    // y einsum for BOTH branches, 32-channel staged tiles
    const int grp = t / 112, l = t - grp * 112;   // grp<2 active, 4 m each
    #pragma unroll 1
    for (int br = 0; br < 2; ++br) {
        const float* pool_h = br ? mh : ph;
        const float* pool_w = br ? mw : pw;
        const float4* ph4 = (const float4*)(pool_h + (size_t)n * (CB * CL));
        const float4* pw4 = (const float4*)(pool_w + (size_t)n * (CB * CL));
        float a0 = 0.f, a1 = 0.f, a2 = 0.f, a3 = 0.f;
        #pragma unroll 1
        for (int cc = 0; cc < CB; cc += 32) {
            __syncthreads();                  // protect previous tile read
            for (int j = t; j < 896; j += 256) {
                if (j < 448) {
                    int c = j / 14, f = j - c * 14;
                    float4 v = ph4[(cc + c) * 14 + f];
                    float* d = &tile[c * 113 + f * 4];
                    d[0] = v.x; d[1] = v.y; d[2] = v.z; d[3] = v.w;
                } else {
                    int j2 = j - 448;
                    int c = j2 / 14, f = j2 - c * 14;
                    float4 v = pw4[(cc + c) * 14 + f];
                    float* d = &tile[c * 113 + 56 + f * 4];
                    d[0] = v.x; d[1] = v.y; d[2] = v.z; d[3] = v.w;
                }
            }
            __syncthreads();
            if (grp < 2) {
                int m0 = grp * 4;
                #pragma unroll 8
                for (int ci = 0; ci < 32; ++ci) {
                    float v = tile[ci * 113 + l];
                    a0 += v * lw1[(m0 + 0) * CB + cc + ci];
                    a1 += v * lw1[(m0 + 1) * CB + cc + ci];
                    a2 += v * lw1[(m0 + 2) * CB + cc + ci];
                    a3 += v * lw1[(m0 + 3) * CB + cc + ci];
                }
            }
        }
        if (grp < 2) {
            int m0 = grp * 4;
            float acc[4] = {a0, a1, a2, a3};
            #pragma unroll
            for (int k = 0; k < 4; ++k) {
                int m = m0 + k;
                float scale = gamma[m] * rsqrtf(rvar[m] + 1e-5f);
                float val = (acc[k] + b1[m] - rmean[m]) * scale + beta[m];
                yl[br * 896 + m * 112 + l] = fmaxf(val, 0.f);
            }
        }
    }
    __syncthreads();

    // gate reduce -> g0,g1
    if (t < 64)
        hid[t] = fmaxf(red[t * 4] + red[t * 4 + 1] + red[t * 4 + 2] + red[t * 4 + 3], 0.f);
    __syncthreads();
    if (t == 0) {
        float l0 = gb2[0], l1 = gb2[1];
        for (int j = 0; j < 64; ++j) { l0 += hid[j] * gw2[j]; l1 += hid[j] * gw2[64 + j]; }
        float mx = fmaxf(l0, l1);
        float e0 = __expf(l0 - mx), e1 = __expf(l1 - mx);
        float inv = 1.f / (e0 + e1);
        gg[0] = e0 * inv; gg[1] = e1 * inv;
    }
    __syncthreads();

    // g-scaled coefficient tables for this chunk's 8 channels
    {
        const float g0 = gg[0], g1 = gg[1];
        for (int task = t; task < 448; task += 256) {
            int ci = task / 56, l2 = task - ci * 56;
            int c = c0 + ci;
            float h0 = bh[c], w0 = bw[c], h1 = h0, w1v = w0;
            #pragma unroll
            for (int m = 0; m < 8; ++m) {
                float whv = wh[c * 8 + m], wwv = ww[c * 8 + m];
                h0  += yl[m * 112 + l2]            * whv;
                w0  += yl[m * 112 + 56 + l2]       * wwv;
                h1  += yl[896 + m * 112 + l2]      * whv;
                w1v += yl[896 + m * 112 + 56 + l2] * wwv;
            }
            tb[task]        = 1.f / (1.f + __expf(-h0));
            tb[448 + task]  = g0 / (1.f + __expf(-w0));
            tb[896 + task]  = 1.f / (1.f + __expf(-h1));
            tb[1344 + task] = g1 / (1.f + __expf(-w1v));
        }
    }
    __syncthreads();

    // persist scaled tables for k_final (L2-hot round trip)
    {
        const float4* ts = (const float4*)tb;
        float4* td = (float4*)(tbl + (size_t)gq * TBLN);
        for (int i = t; i < 448; i += 256) td[i] = ts[i];
    }

    // tsum streaming over the chunk's 8 planes (verified body)
    const float* cH0 = tb;
    const float* cW0 = tb + 448;
    const float* cH1 = tb + 896;
    const float* cW1 = tb + 1344;
    #pragma unroll 1
    for (int i = 0; i < 8; ++i) {
        const float4* xp4 = (const float4*)(x + (size_t)(q0 + i) * PLANE);
        const float4* a4 = (const float4*)(cW0 + i * 56);
        const float4* b4 = (const float4*)(cW1 + i * 56);
        const float* h0p = cH0 + i * 56;
        const float* h1p = cH1 + i * 56;
        float acc = 0.f;
        for (int j = t; j < PLANE4; j += 256) {
            float4 v = xp4[j];
            int h = j / 14, wq = j - h * 14;
            float h0 = h0p[h], h1 = h1p[h];
            float4 a = a4[wq], b = b4[wq];
            acc += v.x * (h0 * a.x + h1 * b.x) + v.y * (h0 * a.y + h1 * b.y)
                 + v.z * (h0 * a.z + h1 * b.z) + v.w * (h0 * a.w + h1 * b.w);
        }
        float s = wave_sum(acc);
        if (ln == 0) part[i * 4 + wv] = s;
    }
    __syncthreads();
    if (t < 8)
        tvec[q0 + t] = (part[t * 4] + part[t * 4 + 1] + part[t * 4 + 2] + part[t * 4 + 3]) * (1.f / PLANE);
}

// ---------------- Kernel 3: s per block, out = x*(attn*s+1). 1024 blocks --------
__global__ __launch_bounds__(256) void k_final(const float* __restrict__ x,
        const float* __restrict__ tbl, const float* __restrict__ tvec,
        const float* __restrict__ cw1, const float* __restrict__ cw2,
        const float* __restrict__ cb2, float* __restrict__ out) {
    __shared__ __align__(16) float tb[1792];
    __shared__ __align__(16) float part_h[256];
    __shared__ float hid[64];
    __shared__ float sS[8];
    const int t = threadIdx.x;
    const int gq = blockIdx.x;
    const int q0 = gq * 8, qn = q0 >> 8, qc0 = q0 & 255;
    {
        const float4* ts = (const float4*)(tbl + (size_t)gq * TBLN);
        float4* td = (float4*)tb;
        for (int i = t; i < 448; i += 256) td[i] = ts[i];   // pre-scaled tables
    }
    // s-gate hidden layer partials (64 j x 4 c-chunks over all 256 threads)
    {
        int j = t & 63, ch = t >> 6;
        const float* tv = tvec + qn * CB + ch * 64;
        const float* wp = cw1 + (size_t)j * CB + ch * 64;
        float a = 0.f;
        #pragma unroll 8
        for (int c = 0; c < 64; ++c) a += tv[c] * wp[c];
        part_h[j * 4 + ch] = a;
    }
    __syncthreads();
    if (t < 64) {
        float4 p = *(const float4*)(part_h + t * 4);
        hid[t] = fmaxf(p.x + p.y + p.z + p.w, 0.f);
    }
    __syncthreads();
    if (t < 8) {                              // s for this chunk's 8 channels
        int c = qc0 + t;
        float a = cb2[c];
        #pragma unroll 8
        for (int j = 0; j < 64; ++j) a += hid[j] * cw2[c * 64 + j];
        sS[t] = 1.f / (1.f + __expf(-a));
    }
    __syncthreads();

    const float* cH0 = tb;
    const float* cW0 = tb + 448;
    const float* cH1 = tb + 896;
    const float* cW1 = tb + 1344;

    #pragma unroll 1
    for (int i = 0; i < 8; ++i) {
        const float sv = sS[i];
        const float4* xp4 = (const float4*)(x + (size_t)(q0 + i) * PLANE);
        float4* op4 = (float4*)(out + (size_t)(q0 + i) * PLANE);
        const float4* a4 = (const float4*)(cW0 + i * 56);
        const float4* b4 = (const float4*)(cW1 + i * 56);
        const float* h0p = cH0 + i * 56;
        const float* h1p = cH1 + i * 56;
        for (int j = t; j < PLANE4; j += 256) {
            float4 v = xp4[j];
            int h = j / 14, wq = j - h * 14;
            float h0 = h0p[h] * sv, h1 = h1p[h] * sv;
            float4 a = a4[wq], b = b4[wq];
            float4 rr;
            rr.x = v.x * (h0 * a.x + h1 * b.x + 1.f);
            rr.y = v.y * (h0 * a.y + h1 * b.y + 1.f);
            rr.z = v.z * (h0 * a.z + h1 * b.z + 1.f);
            rr.w = v.w * (h0 * a.w + h1 * b.w + 1.f);
            op4[j] = rr;
        }
    }
}

extern "C" void kernel_launch(void* const* d_in, const int* in_sizes, int n_in,
                              void* d_out, int out_size, void* d_ws, size_t ws_size,
                              hipStream_t stream) {
    const float* x     = (const float*)d_in[0];
    const float* w1    = (const float*)d_in[1];
    const float* b1    = (const float*)d_in[2];
    const float* gamma = (const float*)d_in[3];
    const float* beta  = (const float*)d_in[4];
    const float* rmean = (const float*)d_in[5];
    const float* rvar  = (const float*)d_in[6];
    const float* wh    = (const float*)d_in[7];
    const float* bh    = (const float*)d_in[8];
    const float* ww    = (const float*)d_in[9];
    const float* bw    = (const float*)d_in[10];
    const float* gw1   = (const float*)d_in[11];
    const float* gw2   = (const float*)d_in[12];
    const float* gb2   = (const float*)d_in[13];
    const float* cw1   = (const float*)d_in[14];
    const float* cw2   = (const float*)d_in[15];
    const float* cb2   = (const float*)d_in[16];
    float* out = (float*)d_out;

    float* w = (float*)d_ws;
    float* ph   = w;                          // POOLSZ each
    float* pw   = ph + POOLSZ;
    float* mh   = pw + POOLSZ;
    float* mw   = mh + POOLSZ;
    float* gap  = mw + POOLSZ;                // NB*CB
    float* tvec = gap + NB * CB;              // NB*CB
    float* tbl  = tvec + NB * CB;             // NCHUNK * TBLN

    k_pool<<<4096, 256, 0, stream>>>(x, ph, pw, mh, mw, gap);
    k_bt<<<1024, 256, 0, stream>>>(x, ph, pw, mh, mw, gap,
                                   w1, b1, gamma, beta, rmean, rvar,
                                   gw1, gw2, gb2, wh, bh, ww, bw,
                                   tvec, tbl);
    k_final<<<1024, 256, 0, stream>>>(x, tbl, tvec, cw1, cw2, cb2, out);
}

// Round 6
// 291.852 us; speedup vs baseline: 1.0722x; 1.0722x over previous
//
#include <hip/hip_runtime.h>
#include <math.h>

#define NB 32
#define CB 256
#define HB 56
#define WB 56
#define PLANE 3136           // floats per (n,c) plane
#define PLANE4 784           // float4 per plane
#define CL 56
#define POOLSZ (NB*CB*CL)
#define NCHUNK 1024          // 8-plane chunks
#define TBLN 1792            // table floats per chunk: H0|W0g|H1|W1g (448 each)

__device__ inline float wave_sum(float v) {
    #pragma unroll
    for (int o = 32; o; o >>= 1) v += __shfl_xor(v, o, 64);
    return v;
}

// ---------------- Kernel 1: pooling. 4096 blocks, 2 planes (verified R4) --------
__global__ __launch_bounds__(256) void k_pool(const float* __restrict__ x,
        float* __restrict__ ph, float* __restrict__ pw,
        float* __restrict__ mh, float* __restrict__ mw, float* __restrict__ gap) {
    __shared__ float tile[2 * 3192];          // two 56x57 planes, 25.5 KB
    const int t = threadIdx.x, wv = t >> 6, ln = t & 63;
    const int pA = blockIdx.x * 2;
    const float4* x4 = (const float4*)(x + (size_t)pA * PLANE);

    float4 v[6];
    #pragma unroll
    for (int u = 0; u < 6; ++u) v[u] = x4[t + u * 256];
    float4 vt;
    const bool tail = t < 32;
    if (tail) vt = x4[t + 1536];
    #pragma unroll
    for (int u = 0; u < 6; ++u) {
        int j = t + u * 256;
        int pl = j >= PLANE4, jj = j - pl * PLANE4;
        int h = jj / 14, wq = jj - h * 14;
        float* d = &tile[pl * 3192 + h * 57 + wq * 4];
        d[0] = v[u].x; d[1] = v[u].y; d[2] = v[u].z; d[3] = v[u].w;
    }
    if (tail) {
        int j = t + 1536;
        int jj = j - PLANE4;                  // always plane 1
        int h = jj / 14, wq = jj - h * 14;
        float* d = &tile[3192 + h * 57 + wq * 4];
        d[0] = vt.x; d[1] = vt.y; d[2] = vt.z; d[3] = vt.w;
    }
    __syncthreads();

    const int pl = wv >> 1;                   // waves 0,1 -> plane A; 2,3 -> B
    const float* tb = &tile[pl * 3192];
    const size_t pidx = (size_t)(pA + pl) * CL;
    if (!(wv & 1)) {                          // even wave: column scans
        if (ln < CL) {
            float s = 0.f, m = -INFINITY;
            #pragma unroll 8
            for (int h = 0; h < HB; ++h) { float vv = tb[h * 57 + ln]; s += vv; m = fmaxf(m, vv); }
            pw[pidx + ln] = s * (1.f / HB);
            mw[pidx + ln] = m;
        }
    } else {                                  // odd wave: row scans + gap
        float s = 0.f, m = -INFINITY;
        if (ln < CL) {
            #pragma unroll 8
            for (int wq = 0; wq < WB; ++wq) { float vv = tb[ln * 57 + wq]; s += vv; m = fmaxf(m, vv); }
            ph[pidx + ln] = s * (1.f / WB);
            mh[pidx + ln] = m;
        }
        float tot = wave_sum(s);              // lanes >=56 contribute 0
        if (ln == 0) gap[pA + pl] = tot * (1.f / PLANE);
    }
}

// ---------------- Kernel 2: redundant y (staging-free) + g + tables + tsum ------
// 1024 blocks; block gq owns planes q0..q0+7 (n = gq>>5, c0 = (gq&31)*8)
__global__ __launch_bounds__(256) void k_bt(const float* __restrict__ x,
        const float* __restrict__ ph, const float* __restrict__ pw,
        const float* __restrict__ mh, const float* __restrict__ mw,
        const float* __restrict__ gap,
        const float* __restrict__ w1, const float* __restrict__ b1,
        const float* __restrict__ gamma, const float* __restrict__ beta,
        const float* __restrict__ rmean, const float* __restrict__ rvar,
        const float* __restrict__ gw1, const float* __restrict__ gw2,
        const float* __restrict__ gb2,
        const float* __restrict__ wh, const float* __restrict__ bh,
        const float* __restrict__ ww, const float* __restrict__ bw,
        float* __restrict__ tvec, float* __restrict__ tbl) {
    __shared__ __align__(16) float w1t[CB * 8];   // [c][m] transposed
    __shared__ float yl[1792];                    // [br][m][l]
    __shared__ __align__(16) float tb[1792];      // H0|W0*g0|H1|W1*g1
    __shared__ float red[256];
    __shared__ float hid[64];
    __shared__ float part[32];
    __shared__ float gg[2];
    const int t = threadIdx.x, wv = t >> 6, ln = t & 63;
    const int gq = blockIdx.x;
    const int n = gq >> 5, c0 = (gq & 31) * 8;
    const int q0 = gq * 8;                        // == n*256 + c0

    // w1t[c*8+m] = w1[m*256+c]  (8 elems/thread, tiny)
    for (int i = t; i < CB * 8; i += 256) w1t[i] = w1[(i & 7) * CB + (i >> 3)];

    // gate hidden-layer partials (verified pattern; gap L2-hot)
    {
        int j = t & 63, ch = t >> 6;
        const float* gv = gap + n * CB + ch * 64;
        const float* wp = gw1 + (size_t)j * CB + ch * 64;
        float a = 0.f;
        #pragma unroll 8
        for (int c = 0; c < 64; ++c) a += gv[c] * wp[c];
        red[j * 4 + ch] = a;
    }
    __syncthreads();                              // w1t + red ready

    if (t < 64)
        hid[t] = fmaxf(red[t * 4] + red[t * 4 + 1] + red[t * 4 + 2] + red[t * 4 + 3], 0.f);

    // redundant y einsum, staging-free: thread owns (br, l), computes 8 m's
    if (t < 224) {
        const int br = t / 112, l = t - br * 112;
        const int lofs = (l < 56) ? l : l - 56;
        const float* pb = (br == 0) ? (l < 56 ? ph : pw) : (l < 56 ? mh : mw);
        const float* pp = pb + (size_t)n * (CB * CL) + lofs;
        float acc[8] = {0.f, 0.f, 0.f, 0.f, 0.f, 0.f, 0.f, 0.f};
        #pragma unroll 4
        for (int c = 0; c < CB; ++c) {
            float v = pp[c * CL];                 // coalesced per lane-group, L2-hot
            float4 wa = *(const float4*)&w1t[c * 8];
            float4 wb = *(const float4*)&w1t[c * 8 + 4];
            acc[0] += v * wa.x; acc[1] += v * wa.y;
            acc[2] += v * wa.z; acc[3] += v * wa.w;
            acc[4] += v * wb.x; acc[5] += v * wb.y;
            acc[6] += v * wb.z; acc[7] += v * wb.w;
        }
        #pragma unroll
        for (int m = 0; m < 8; ++m) {
            float scale = gamma[m] * rsqrtf(rvar[m] + 1e-5f);
            float val = (acc[m] + b1[m] - rmean[m]) * scale + beta[m];
            yl[br * 896 + m * 112 + l] = fmaxf(val, 0.f);
        }
    }
    __syncthreads();                              // yl + hid ready

    if (wv == 0) {                                // gate softmax via wave-0 shuffle
        float h = hid[ln];
        float p0 = wave_sum(h * gw2[ln]);
        float p1 = wave_sum(h * gw2[64 + ln]);
        if (ln == 0) {
            float l0 = gb2[0] + p0, l1 = gb2[1] + p1;
            float mx = fmaxf(l0, l1);
            float e0 = __expf(l0 - mx), e1 = __expf(l1 - mx);
            float inv = 1.f / (e0 + e1);
            gg[0] = e0 * inv; gg[1] = e1 * inv;
        }
    }
    __syncthreads();                              // gg ready

    // g-scaled coefficient tables for this chunk's 8 channels (verified R5 body)
    {
        const float g0 = gg[0], g1 = gg[1];
        for (int task = t; task < 448; task += 256) {
            int ci = task / 56, l2 = task - ci * 56;
            int c = c0 + ci;
            float h0 = bh[c], w0 = bw[c], h1 = h0, w1v = w0;
            #pragma unroll
            for (int m = 0; m < 8; ++m) {
                float whv = wh[c * 8 + m], wwv = ww[c * 8 + m];
                h0  += yl[m * 112 + l2]            * whv;
                w0  += yl[m * 112 + 56 + l2]       * wwv;
                h1  += yl[896 + m * 112 + l2]      * whv;
                w1v += yl[896 + m * 112 + 56 + l2] * wwv;
            }
            tb[task]        = 1.f / (1.f + __expf(-h0));
            tb[448 + task]  = g0 / (1.f + __expf(-w0));
            tb[896 + task]  = 1.f / (1.f + __expf(-h1));
            tb[1344 + task] = g1 / (1.f + __expf(-w1v));
        }
    }
    __syncthreads();                              // tb ready

    // persist scaled tables for k_final (L2-hot round trip)
    {
        const float4* ts = (const float4*)tb;
        float4* td = (float4*)(tbl + (size_t)gq * TBLN);
        for (int i = t; i < 448; i += 256) td[i] = ts[i];
    }

    // tsum streaming over the chunk's 8 planes (verified R5 body)
    const float* cH0 = tb;
    const float* cW0 = tb + 448;
    const float* cH1 = tb + 896;
    const float* cW1 = tb + 1344;
    #pragma unroll 1
    for (int i = 0; i < 8; ++i) {
        const float4* xp4 = (const float4*)(x + (size_t)(q0 + i) * PLANE);
        const float4* a4 = (const float4*)(cW0 + i * 56);
        const float4* b4 = (const float4*)(cW1 + i * 56);
        const float* h0p = cH0 + i * 56;
        const float* h1p = cH1 + i * 56;
        float acc = 0.f;
        for (int j = t; j < PLANE4; j += 256) {
            float4 v = xp4[j];
            int h = j / 14, wq = j - h * 14;
            float h0 = h0p[h], h1 = h1p[h];
            float4 a = a4[wq], b = b4[wq];
            acc += v.x * (h0 * a.x + h1 * b.x) + v.y * (h0 * a.y + h1 * b.y)
                 + v.z * (h0 * a.z + h1 * b.z) + v.w * (h0 * a.w + h1 * b.w);
        }
        float s = wave_sum(acc);
        if (ln == 0) part[i * 4 + wv] = s;
    }
    __syncthreads();
    if (t < 8)
        tvec[q0 + t] = (part[t * 4] + part[t * 4 + 1] + part[t * 4 + 2] + part[t * 4 + 3]) * (1.f / PLANE);
}

// ---------------- Kernel 3: s per block, out = x*(attn*s+1). 1024 blocks --------
// (verified R5 version, unchanged)
__global__ __launch_bounds__(256) void k_final(const float* __restrict__ x,
        const float* __restrict__ tbl, const float* __restrict__ tvec,
        const float* __restrict__ cw1, const float* __restrict__ cw2,
        const float* __restrict__ cb2, float* __restrict__ out) {
    __shared__ __align__(16) float tb[1792];
    __shared__ __align__(16) float part_h[256];
    __shared__ float hid[64];
    __shared__ float sS[8];
    const int t = threadIdx.x;
    const int gq = blockIdx.x;
    const int q0 = gq * 8, qn = q0 >> 8, qc0 = q0 & 255;
    {
        const float4* ts = (const float4*)(tbl + (size_t)gq * TBLN);
        float4* td = (float4*)tb;
        for (int i = t; i < 448; i += 256) td[i] = ts[i];   // pre-scaled tables
    }
    // s-gate hidden layer partials (64 j x 4 c-chunks over all 256 threads)
    {
        int j = t & 63, ch = t >> 6;
        const float* tv = tvec + qn * CB + ch * 64;
        const float* wp = cw1 + (size_t)j * CB + ch * 64;
        float a = 0.f;
        #pragma unroll 8
        for (int c = 0; c < 64; ++c) a += tv[c] * wp[c];
        part_h[j * 4 + ch] = a;
    }
    __syncthreads();
    if (t < 64) {
        float4 p = *(const float4*)(part_h + t * 4);
        hid[t] = fmaxf(p.x + p.y + p.z + p.w, 0.f);
    }
    __syncthreads();
    if (t < 8) {                              // s for this chunk's 8 channels
        int c = qc0 + t;
        float a = cb2[c];
        #pragma unroll 8
        for (int j = 0; j < 64; ++j) a += hid[j] * cw2[c * 64 + j];
        sS[t] = 1.f / (1.f + __expf(-a));
    }
    __syncthreads();

    const float* cH0 = tb;
    const float* cW0 = tb + 448;
    const float* cH1 = tb + 896;
    const float* cW1 = tb + 1344;

    #pragma unroll 1
    for (int i = 0; i < 8; ++i) {
        const float sv = sS[i];
        const float4* xp4 = (const float4*)(x + (size_t)(q0 + i) * PLANE);
        float4* op4 = (float4*)(out + (size_t)(q0 + i) * PLANE);
        const float4* a4 = (const float4*)(cW0 + i * 56);
        const float4* b4 = (const float4*)(cW1 + i * 56);
        const float* h0p = cH0 + i * 56;
        const float* h1p = cH1 + i * 56;
        for (int j = t; j < PLANE4; j += 256) {
            float4 v = xp4[j];
            int h = j / 14, wq = j - h * 14;
            float h0 = h0p[h] * sv, h1 = h1p[h] * sv;
            float4 a = a4[wq], b = b4[wq];
            float4 rr;
            rr.x = v.x * (h0 * a.x + h1 * b.x + 1.f);
            rr.y = v.y * (h0 * a.y + h1 * b.y + 1.f);
            rr.z = v.z * (h0 * a.z + h1 * b.z + 1.f);
            rr.w = v.w * (h0 * a.w + h1 * b.w + 1.f);
            op4[j] = rr;
        }
    }
}

extern "C" void kernel_launch(void* const* d_in, const int* in_sizes, int n_in,
                              void* d_out, int out_size, void* d_ws, size_t ws_size,
                              hipStream_t stream) {
    const float* x     = (const float*)d_in[0];
    const float* w1    = (const float*)d_in[1];
    const float* b1    = (const float*)d_in[2];
    const float* gamma = (const float*)d_in[3];
    const float* beta  = (const float*)d_in[4];
    const float* rmean = (const float*)d_in[5];
    const float* rvar  = (const float*)d_in[6];
    const float* wh    = (const float*)d_in[7];
    const float* bh    = (const float*)d_in[8];
    const float* ww    = (const float*)d_in[9];
    const float* bw    = (const float*)d_in[10];
    const float* gw1   = (const float*)d_in[11];
    const float* gw2   = (const float*)d_in[12];
    const float* gb2   = (const float*)d_in[13];
    const float* cw1   = (const float*)d_in[14];
    const float* cw2   = (const float*)d_in[15];
    const float* cb2   = (const float*)d_in[16];
    float* out = (float*)d_out;

    float* w = (float*)d_ws;
    float* ph   = w;                          // POOLSZ each
    float* pw   = ph + POOLSZ;
    float* mh   = pw + POOLSZ;
    float* mw   = mh + POOLSZ;
    float* gap  = mw + POOLSZ;                // NB*CB
    float* tvec = gap + NB * CB;              // NB*CB
    float* tbl  = tvec + NB * CB;             // NCHUNK * TBLN

    k_pool<<<4096, 256, 0, stream>>>(x, ph, pw, mh, mw, gap);
    k_bt<<<1024, 256, 0, stream>>>(x, ph, pw, mh, mw, gap,
                                   w1, b1, gamma, beta, rmean, rvar,
                                   gw1, gw2, gb2, wh, bh, ww, bw,
                                   tvec, tbl);
    k_final<<<1024, 256, 0, stream>>>(x, tbl, tvec, cw1, cw2, cb2, out);
}